// Round 7
// baseline (502.445 us; speedup 1.0000x reference)
//
#include <hip/hip_runtime.h>
#include <hip/hip_bf16.h>

typedef __bf16 bf16x8 __attribute__((ext_vector_type(8)));
typedef __bf16 bf16x4 __attribute__((ext_vector_type(4)));
typedef float f32x4 __attribute__((ext_vector_type(4)));
typedef float f32x8 __attribute__((ext_vector_type(8)));

#define B_ 8
#define L_ 1024
#define D_ 1024
#define H_ 16
#define DPH_ 64
#define MAXREL_ 32
#define NREL_ 65

__device__ __forceinline__ f32x4 mfma16x16x32(bf16x8 a, bf16x8 b, f32x4 c) {
    return __builtin_amdgcn_mfma_f32_16x16x32_bf16(a, b, c, 0, 0, 0);
}

__device__ __forceinline__ bf16x8 ld_any(const float* p) {
    f32x8 v = *(const f32x8*)p;
    bf16x8 r;
    #pragma unroll
    for (int i = 0; i < 8; ++i) r[i] = (__bf16)v[i];
    return r;
}
__device__ __forceinline__ bf16x8 ld_any(const __bf16* p) { return *(const bf16x8*)p; }

// ---------------------------------------------------------------------------
// Fused QKV projection: z = blockIdx.z selects (X, W, bias, out, scale, mode).
// 128x128 tile, LDS-staged with 16B-chunk XOR swizzle, reg prefetch.
// z==2 (V) stores transposed: Vt[(m>>10)<<20 | n*1024 | m&1023].
// ---------------------------------------------------------------------------
__global__ __launch_bounds__(256) void gemm_qkv(
    const float* __restrict__ Xq, const float* __restrict__ Xk,
    const float* __restrict__ Xv,
    const float* __restrict__ W0, const float* __restrict__ W1,
    const float* __restrict__ W2,
    const float* __restrict__ b0, const float* __restrict__ b1,
    const float* __restrict__ b2,
    __bf16* __restrict__ O0, __bf16* __restrict__ O1, __bf16* __restrict__ O2)
{
    __shared__ __bf16 sA[128 * 64];
    __shared__ __bf16 sB[128 * 64];

    const int z = blockIdx.z;
    const float* X  = z == 0 ? Xq : (z == 1 ? Xk : Xv);
    const float* Wt = z == 0 ? W0 : (z == 1 ? W1 : W2);
    const float* bias = z == 0 ? b0 : (z == 1 ? b1 : b2);
    __bf16* outp = z == 0 ? O0 : (z == 1 ? O1 : O2);
    const float scale = z == 0 ? 0.125f : 1.0f;

    const int tid = threadIdx.x;
    const int M = B_ * L_, N = D_, K = D_;
    const int nbn = N >> 7;
    const int nwg = (M >> 7) * nbn;
    const int wg  = ((int)blockIdx.x & 7) * (nwg >> 3) + ((int)blockIdx.x >> 3);
    const int row0 = (wg / nbn) * 128, col0 = (wg % nbn) * 128;
    const int lane = tid & 63, w = tid >> 6, lr = lane & 15, lk = lane >> 4;
    const int wm = w >> 1, wn = w & 1;
    const int srow = tid >> 3;
    const int schk = tid & 7;

    bf16x8 ra[4], rb[4];
    f32x4 acc[4][4];
    #pragma unroll
    for (int a = 0; a < 4; ++a)
        #pragma unroll
        for (int b = 0; b < 4; ++b) acc[a][b] = (f32x4){0.f, 0.f, 0.f, 0.f};

    const int nkt = K >> 6;
    {
        const int kc = schk * 8;
        #pragma unroll
        for (int u = 0; u < 4; ++u) {
            const int r = u * 32 + srow;
            ra[u] = ld_any(X  + (size_t)(row0 + r) * K + kc);
            rb[u] = ld_any(Wt + (size_t)(col0 + r) * K + kc);
        }
    }
    for (int kt = 0; kt < nkt; ++kt) {
        __syncthreads();
        #pragma unroll
        for (int u = 0; u < 4; ++u) {
            const int r = u * 32 + srow;
            *(bf16x8*)&sA[r * 64 + ((schk ^ (r & 7)) * 8)] = ra[u];
            *(bf16x8*)&sB[r * 64 + ((schk ^ (r & 7)) * 8)] = rb[u];
        }
        __syncthreads();
        if (kt + 1 < nkt) {
            const int kc = (kt + 1) * 64 + schk * 8;
            #pragma unroll
            for (int u = 0; u < 4; ++u) {
                const int r = u * 32 + srow;
                ra[u] = ld_any(X  + (size_t)(row0 + r) * K + kc);
                rb[u] = ld_any(Wt + (size_t)(col0 + r) * K + kc);
            }
        }
        #pragma unroll
        for (int kk = 0; kk < 2; ++kk) {
            bf16x8 af[4], bf[4];
            #pragma unroll
            for (int mi = 0; mi < 4; ++mi) {
                const int r = wm * 64 + mi * 16 + lr;
                af[mi] = *(const bf16x8*)&sA[r * 64 + (((kk * 4 + lk) ^ (r & 7)) * 8)];
            }
            #pragma unroll
            for (int ni = 0; ni < 4; ++ni) {
                const int r = wn * 64 + ni * 16 + lr;
                bf[ni] = *(const bf16x8*)&sB[r * 64 + (((kk * 4 + lk) ^ (r & 7)) * 8)];
            }
            #pragma unroll
            for (int mi = 0; mi < 4; ++mi)
                #pragma unroll
                for (int ni = 0; ni < 4; ++ni)
                    acc[mi][ni] = mfma16x16x32(af[mi], bf[ni], acc[mi][ni]);
        }
    }

    #pragma unroll
    for (int ni = 0; ni < 4; ++ni) {
        const int n = col0 + wn * 64 + ni * 16 + lr;
        const float bv = bias[n];
        #pragma unroll
        for (int mi = 0; mi < 4; ++mi) {
            const int m0 = row0 + wm * 64 + mi * 16 + lk * 4;
            if (z != 2) {
                #pragma unroll
                for (int i = 0; i < 4; ++i)
                    outp[(size_t)(m0 + i) * N + n] =
                        (__bf16)((acc[mi][ni][i] + bv) * scale);
            } else {
                bf16x4 v4;
                #pragma unroll
                for (int i = 0; i < 4; ++i) v4[i] = (__bf16)(acc[mi][ni][i] + bv);
                *(bf16x4*)(outp + ((size_t)(m0 >> 10) << 20)
                           + (size_t)n * L_ + (m0 & 1023)) = v4;
            }
        }
    }
}

// out-projection: A bf16 MxK, W f32 NxK -> f32 out (same 128-tile body)
__global__ __launch_bounds__(256) void gemm_out(
    const __bf16* __restrict__ X, const float* __restrict__ Wt,
    const float* __restrict__ bias, float* __restrict__ outp)
{
    __shared__ __bf16 sA[128 * 64];
    __shared__ __bf16 sB[128 * 64];

    const int tid = threadIdx.x;
    const int M = B_ * L_, N = D_, K = D_;
    const int nbn = N >> 7;
    const int nwg = (M >> 7) * nbn;
    const int wg  = ((int)blockIdx.x & 7) * (nwg >> 3) + ((int)blockIdx.x >> 3);
    const int row0 = (wg / nbn) * 128, col0 = (wg % nbn) * 128;
    const int lane = tid & 63, w = tid >> 6, lr = lane & 15, lk = lane >> 4;
    const int wm = w >> 1, wn = w & 1;
    const int srow = tid >> 3;
    const int schk = tid & 7;

    bf16x8 ra[4], rb[4];
    f32x4 acc[4][4];
    #pragma unroll
    for (int a = 0; a < 4; ++a)
        #pragma unroll
        for (int b = 0; b < 4; ++b) acc[a][b] = (f32x4){0.f, 0.f, 0.f, 0.f};

    const int nkt = K >> 6;
    {
        const int kc = schk * 8;
        #pragma unroll
        for (int u = 0; u < 4; ++u) {
            const int r = u * 32 + srow;
            ra[u] = ld_any(X  + (size_t)(row0 + r) * K + kc);
            rb[u] = ld_any(Wt + (size_t)(col0 + r) * K + kc);
        }
    }
    for (int kt = 0; kt < nkt; ++kt) {
        __syncthreads();
        #pragma unroll
        for (int u = 0; u < 4; ++u) {
            const int r = u * 32 + srow;
            *(bf16x8*)&sA[r * 64 + ((schk ^ (r & 7)) * 8)] = ra[u];
            *(bf16x8*)&sB[r * 64 + ((schk ^ (r & 7)) * 8)] = rb[u];
        }
        __syncthreads();
        if (kt + 1 < nkt) {
            const int kc = (kt + 1) * 64 + schk * 8;
            #pragma unroll
            for (int u = 0; u < 4; ++u) {
                const int r = u * 32 + srow;
                ra[u] = ld_any(X  + (size_t)(row0 + r) * K + kc);
                rb[u] = ld_any(Wt + (size_t)(col0 + r) * K + kc);
            }
        }
        #pragma unroll
        for (int kk = 0; kk < 2; ++kk) {
            bf16x8 af[4], bf[4];
            #pragma unroll
            for (int mi = 0; mi < 4; ++mi) {
                const int r = wm * 64 + mi * 16 + lr;
                af[mi] = *(const bf16x8*)&sA[r * 64 + (((kk * 4 + lk) ^ (r & 7)) * 8)];
            }
            #pragma unroll
            for (int ni = 0; ni < 4; ++ni) {
                const int r = wn * 64 + ni * 16 + lr;
                bf[ni] = *(const bf16x8*)&sB[r * 64 + (((kk * 4 + lk) ^ (r & 7)) * 8)];
            }
            #pragma unroll
            for (int mi = 0; mi < 4; ++mi)
                #pragma unroll
                for (int ni = 0; ni < 4; ++ni)
                    acc[mi][ni] = mfma16x16x32(af[mi], bf[ni], acc[mi][ni]);
        }
    }

    #pragma unroll
    for (int ni = 0; ni < 4; ++ni) {
        const int n = col0 + wn * 64 + ni * 16 + lr;
        const float bv = bias[n];
        #pragma unroll
        for (int mi = 0; mi < 4; ++mi) {
            const int m0 = row0 + wm * 64 + mi * 16 + lk * 4;
            #pragma unroll
            for (int i = 0; i < 4; ++i)
                outp[(size_t)(m0 + i) * N + n] = acc[mi][ni][i] + bv;
        }
    }
}

// ---------------------------------------------------------------------------
// Attention v4: no sP. PV A-frags via intra-wave shuffles; each wave computes
// ctx partials for all 64 d over its 256 keys; cross-wave sum via s_acc.
// Far-field waves (no rel-band overlap) skip the LDS bias gather entirely.
// rel-term via 2 MFMAs against transposed relT. LDS ~36KB -> 4 blocks/CU.
// ---------------------------------------------------------------------------
__global__ __launch_bounds__(256, 4) void attn_v4(
    const __bf16* __restrict__ Q, const __bf16* __restrict__ K,
    const __bf16* __restrict__ Vt, const int* __restrict__ mask,
    const float* __restrict__ relg, __bf16* __restrict__ ctx,
    float* __restrict__ attn0)
{
    __shared__ float s_rq[16][68];
    __shared__ float s_arel[16][68];
    __shared__ __bf16 s_relT[64][80];     // relT[d][j] = rel_emb[j][d]
    __shared__ float s_acc[4][16][66];
    __shared__ float s_rsum[4][16];
    __shared__ unsigned s_mbits[32];

    const int tid = threadIdx.x;
    const int wg = ((int)blockIdx.x & 7) * 1024 + ((int)blockIdx.x >> 3);
    const int qb = wg & 63, h = (wg >> 6) & 15, b = wg >> 10;
    const int q0 = qb * 16;
    const int lane = tid & 63, w = tid >> 6, lr = lane & 15, lk = lane >> 4;
    const size_t bh = (size_t)b * (L_ * D_) + (size_t)h * DPH_;
    const int wk0 = w * 256;

    // Q fragments (B-operand): lane lr -> q-row q0+lr
    const __bf16* qp = Q + bh + (size_t)(q0 + lr) * D_ + 8 * lk;
    const bf16x8 qf0 = *(const bf16x8*)qp;
    const bf16x8 qf1 = *(const bf16x8*)(qp + 32);

    // ---- staging: mask bitset, relT transpose, arel zero, rq via MFMA ----
    #pragma unroll
    for (int rr = 0; rr < 4; ++rr) {
        const int k = rr * 256 + w * 64 + lane;
        const unsigned long long bal = __ballot(mask[b * L_ + k] != 0);
        if (lane == 0) {
            s_mbits[rr * 8 + w * 2]     = (unsigned)bal;
            s_mbits[rr * 8 + w * 2 + 1] = (unsigned)(bal >> 32);
        }
    }
    for (int i = tid; i < NREL_ * DPH_; i += 256)
        s_relT[i & 63][i >> 6] = (__bf16)relg[i];
    for (int i = tid; i < 16 * 68; i += 256) ((float*)s_arel)[i] = 0.f;

    for (int jt = w; jt < 5; jt += (w == 0 ? 4 : 8)) {
        const int jr = jt * 16 + lr;
        const int jc = jr > 64 ? 64 : jr;
        const float* rp = relg + jc * 64 + 8 * lk;
        f32x4 rq = {0.f, 0.f, 0.f, 0.f};
        rq = mfma16x16x32(ld_any(rp), qf0, rq);
        rq = mfma16x16x32(ld_any(rp + 32), qf1, rq);
        #pragma unroll
        for (int i = 0; i < 4; ++i) {
            const int jj = jt * 16 + lk * 4 + i;
            if (jj <= 64) s_rq[lr][jj] = rq[i];
        }
    }
    __syncthreads();   // barrier A

    const float rq0  = s_rq[lr][0];
    const float rq64 = s_rq[lr][64];
    unsigned mw[8];
    #pragma unroll
    for (int t = 0; t < 8; ++t) mw[t] = s_mbits[w * 8 + t];

    // ---- QK^T -> p[16][4] (groups of 2 kt, 4 loads in flight) ----
    float p[16][4];
    #pragma unroll
    for (int g = 0; g < 8; ++g) {
        bf16x8 kf[2][2];
        #pragma unroll
        for (int t = 0; t < 2; ++t) {
            const __bf16* kp = K + bh
                + (size_t)(wk0 + (g * 2 + t) * 16 + lr) * D_ + 8 * lk;
            kf[t][0] = *(const bf16x8*)kp;
            kf[t][1] = *(const bf16x8*)(kp + 32);
        }
        #pragma unroll
        for (int t = 0; t < 2; ++t) {
            f32x4 acc = {0.f, 0.f, 0.f, 0.f};
            acc = mfma16x16x32(kf[t][0], qf0, acc);
            acc = mfma16x16x32(kf[t][1], qf1, acc);
            #pragma unroll
            for (int i = 0; i < 4; ++i) p[g * 2 + t][i] = acc[i];
        }
    }

    // ---- bias + mask + exp + row-sum; arel buckets ----
    // wave-uniform side: -1 all keys left of rel band, +1 right, 0 diagonal
    const int side = (wk0 + 255 < q0 - 31) ? -1 : (wk0 > q0 + 46 ? 1 : 0);
    float sum = 0.f;
    if (side == 0) {
        float c0 = 0.f, c64 = 0.f;
        #pragma unroll
        for (int kt = 0; kt < 16; ++kt) {
            const int kb = wk0 + kt * 16 + lk * 4;
            const unsigned mword = mw[kt >> 1];
            #pragma unroll
            for (int i = 0; i < 4; ++i) {
                const int k = kb + i;
                const int dd = k - (q0 + lr);
                int j = dd + MAXREL_;
                j = j < 0 ? 0 : (j > 64 ? 64 : j);
                const float v = p[kt][i] + s_rq[lr][j];
                const float e = ((mword >> (k & 31)) & 1u) ? 0.f : __expf(v);
                p[kt][i] = e;
                sum += e;
                if (dd <= -MAXREL_)      c0  += e;
                else if (dd >= MAXREL_)  c64 += e;
                else                     s_arel[lr][dd + MAXREL_] = e;
            }
        }
        c0  += __shfl_xor(c0, 16, 64);  c0  += __shfl_xor(c0, 32, 64);
        c64 += __shfl_xor(c64, 16, 64); c64 += __shfl_xor(c64, 32, 64);
        sum += __shfl_xor(sum, 16, 64); sum += __shfl_xor(sum, 32, 64);
        if (lane < 16) {
            s_rsum[w][lr] = sum;
            if (c0  != 0.f) atomicAdd(&s_arel[lr][0],  c0);
            if (c64 != 0.f) atomicAdd(&s_arel[lr][64], c64);
        }
    } else {
        const float rqf = side < 0 ? rq0 : rq64;
        #pragma unroll
        for (int kt = 0; kt < 16; ++kt) {
            const int kb = wk0 + kt * 16 + lk * 4;
            const unsigned mword = mw[kt >> 1];
            #pragma unroll
            for (int i = 0; i < 4; ++i) {
                const float e = ((mword >> ((kb + i) & 31)) & 1u)
                              ? 0.f : __expf(p[kt][i] + rqf);
                p[kt][i] = e;
                sum += e;
            }
        }
        sum += __shfl_xor(sum, 16, 64); sum += __shfl_xor(sum, 32, 64);
        if (lane < 16) {
            s_rsum[w][lr] = sum;
            atomicAdd(&s_arel[lr][side < 0 ? 0 : 64], sum);
        }
    }
    __syncthreads();   // barrier B1: s_rsum + s_arel complete

    // ---- attn0 (h==0): normalized f32 stores ----
    if (h == 0) {
        const float inv = 1.f / (s_rsum[0][lr] + s_rsum[1][lr]
                               + s_rsum[2][lr] + s_rsum[3][lr]);
        float* a0p = attn0 + ((size_t)b * L_ + q0 + lr) * L_;
        #pragma unroll
        for (int kt = 0; kt < 16; ++kt) {
            const int kb = wk0 + kt * 16 + lk * 4;
            f32x4 st;
            #pragma unroll
            for (int i = 0; i < 4; ++i) st[i] = p[kt][i] * inv;
            *(f32x4*)&a0p[kb] = st;
        }
    }

    // ---- pack p -> bf16 pairs pk[kt*2+half] ----
    unsigned pk[32];
    #pragma unroll
    for (int kt = 0; kt < 16; ++kt) {
        #pragma unroll
        for (int hf = 0; hf < 2; ++hf) {
            union { unsigned u; __bf16 x[2]; } t;
            t.x[0] = (__bf16)p[kt][2 * hf];
            t.x[1] = (__bf16)p[kt][2 * hf + 1];
            pk[kt * 2 + hf] = t.u;
        }
    }

    // ---- PV: per k-tile t (32 keys): A-frag via 8 shfl, 4 MFMA (all d) ----
    f32x4 acc[4];
    #pragma unroll
    for (int dt = 0; dt < 4; ++dt) acc[dt] = (f32x4){0.f, 0.f, 0.f, 0.f};
    const __bf16* vrow = Vt + ((size_t)b << 20)
                       + (size_t)(h * DPH_ + lr) * L_ + wk0 + 8 * lk;
    const int s0 = lr + 32 * (lk & 1);
    const int s1 = s0 + 16;
    const bool hi = (lk >> 1) != 0;
    #pragma unroll
    for (int t = 0; t < 8; ++t) {
        bf16x8 vf[4];
        #pragma unroll
        for (int dt = 0; dt < 4; ++dt)
            vf[dt] = *(const bf16x8*)(vrow + (size_t)dt * 16 * L_ + t * 32);
        union { unsigned u[4]; bf16x8 v; } ua;
        {
            const unsigned aE0 = __shfl((int)pk[4 * t + 0], s0, 64);
            const unsigned aO0 = __shfl((int)pk[4 * t + 2], s0, 64);
            const unsigned aE1 = __shfl((int)pk[4 * t + 1], s0, 64);
            const unsigned aO1 = __shfl((int)pk[4 * t + 3], s0, 64);
            const unsigned bE0 = __shfl((int)pk[4 * t + 0], s1, 64);
            const unsigned bO0 = __shfl((int)pk[4 * t + 2], s1, 64);
            const unsigned bE1 = __shfl((int)pk[4 * t + 1], s1, 64);
            const unsigned bO1 = __shfl((int)pk[4 * t + 3], s1, 64);
            ua.u[0] = hi ? aO0 : aE0;
            ua.u[1] = hi ? aO1 : aE1;
            ua.u[2] = hi ? bO0 : bE0;
            ua.u[3] = hi ? bO1 : bE1;
        }
        #pragma unroll
        for (int dt = 0; dt < 4; ++dt)
            acc[dt] = mfma16x16x32(ua.v, vf[dt], acc[dt]);
    }
    #pragma unroll
    for (int dt = 0; dt < 4; ++dt)
        #pragma unroll
        for (int i = 0; i < 4; ++i)
            s_acc[w][lk * 4 + i][dt * 16 + lr] = acc[dt][i];
    __syncthreads();   // barrier B2

    // ---- rel-term via MFMA (wave w owns d-tile w) + cross-wave sum ----
    bf16x8 af1, af2;
    {
        f32x4 lo = *(const f32x4*)&s_arel[lr][8 * lk];
        f32x4 hi4 = *(const f32x4*)&s_arel[lr][8 * lk + 4];
        #pragma unroll
        for (int i = 0; i < 4; ++i) { af1[i] = (__bf16)lo[i]; af1[4 + i] = (__bf16)hi4[i]; }
        lo  = *(const f32x4*)&s_arel[lr][32 + 8 * lk];
        hi4 = *(const f32x4*)&s_arel[lr][32 + 8 * lk + 4];
        #pragma unroll
        for (int i = 0; i < 4; ++i) { af2[i] = (__bf16)lo[i]; af2[4 + i] = (__bf16)hi4[i]; }
    }
    const bf16x8 bf1 = *(const bf16x8*)&s_relT[w * 16 + lr][8 * lk];
    const bf16x8 bf2 = *(const bf16x8*)&s_relT[w * 16 + lr][32 + 8 * lk];
    f32x4 crel = {0.f, 0.f, 0.f, 0.f};
    crel = mfma16x16x32(af1, bf1, crel);
    crel = mfma16x16x32(af2, bf2, crel);
    const float r64 = (float)s_relT[w * 16 + lr][64];

    #pragma unroll
    for (int i = 0; i < 4; ++i) {
        const int q = lk * 4 + i;
        float f = crel[i] + s_arel[q][64] * r64;
        #pragma unroll
        for (int w2 = 0; w2 < 4; ++w2) f += s_acc[w2][q][w * 16 + lr];
        const float invq = 1.f / (s_rsum[0][q] + s_rsum[1][q]
                                + s_rsum[2][q] + s_rsum[3][q]);
        ctx[((size_t)b * L_ + q0 + q) * D_ + h * DPH_ + w * 16 + lr] =
            (__bf16)(f * invq);
    }
}

extern "C" void kernel_launch(void* const* d_in, const int* in_sizes, int n_in,
                              void* d_out, int out_size, void* d_ws, size_t ws_size,
                              hipStream_t stream) {
    const float* key   = (const float*)d_in[0];
    const float* value = (const float*)d_in[1];
    const float* query = (const float*)d_in[2];
    const int*   mask  = (const int*)d_in[3];
    const float* Wq = (const float*)d_in[4];
    const float* bq = (const float*)d_in[5];
    const float* Wk = (const float*)d_in[6];
    const float* bk = (const float*)d_in[7];
    const float* Wv = (const float*)d_in[8];
    const float* bv = (const float*)d_in[9];
    const float* Wo = (const float*)d_in[10];
    const float* bo = (const float*)d_in[11];
    const float* relg = (const float*)d_in[12];

    float* out   = (float*)d_out;
    float* attn0 = out + (size_t)B_ * L_ * D_;

    char* ws = (char*)d_ws;
    __bf16* Qw   = (__bf16*)(ws);
    __bf16* Kw   = (__bf16*)(ws + ((size_t)16 << 20));
    __bf16* Vtw  = (__bf16*)(ws + ((size_t)32 << 20));
    __bf16* Ctxw = (__bf16*)(ws + ((size_t)48 << 20));

    const dim3 blk(256);
    const int ngemm = (B_ * L_ / 128) * (D_ / 128);   // 512

    gemm_qkv<<<dim3(ngemm, 1, 3), blk, 0, stream>>>(
        query, key, value, Wq, Wk, Wv, bq, bk, bv, Qw, Kw, Vtw);

    attn_v4<<<B_ * H_ * (L_ / 16), blk, 0, stream>>>(
        Qw, Kw, Vtw, mask, relg, Ctxw, attn0);

    gemm_out<<<ngemm, blk, 0, stream>>>(Ctxw, Wo, bo, out);
}

// Round 8
// 238.348 us; speedup vs baseline: 2.1080x; 2.1080x over previous
//
#include <hip/hip_runtime.h>
#include <hip/hip_bf16.h>

typedef __bf16 bf16x8 __attribute__((ext_vector_type(8)));
typedef __bf16 bf16x4 __attribute__((ext_vector_type(4)));
typedef float f32x4 __attribute__((ext_vector_type(4)));
typedef float f32x8 __attribute__((ext_vector_type(8)));

#define B_ 8
#define L_ 1024
#define D_ 1024
#define H_ 16
#define DPH_ 64
#define MAXREL_ 32
#define NREL_ 65

__device__ __forceinline__ f32x4 mfma16x16x32(bf16x8 a, bf16x8 b, f32x4 c) {
    return __builtin_amdgcn_mfma_f32_16x16x32_bf16(a, b, c, 0, 0, 0);
}

__device__ __forceinline__ bf16x8 ld_any(const float* p) {
    f32x8 v = *(const f32x8*)p;
    bf16x8 r;
    #pragma unroll
    for (int i = 0; i < 8; ++i) r[i] = (__bf16)v[i];
    return r;
}
__device__ __forceinline__ bf16x8 ld_any(const __bf16* p) { return *(const bf16x8*)p; }

// ---------------------------------------------------------------------------
// 128x128-tile GEMM (R5-proven). LDS XOR-swizzled staging + reg prefetch.
// MODE 0: bf16 out[m*N+n]; MODE 1: bf16 Vt[(m>>10)<<20 | n*1024 | m&1023];
// MODE 2: f32 out[m*N+n].
// ---------------------------------------------------------------------------
template <int MODE, typename TA>
__global__ __launch_bounds__(256) void gemm128(
    const TA* __restrict__ X, const float* __restrict__ Wt,
    const float* __restrict__ bias, void* __restrict__ outp,
    int M, int N, int K, float scale)
{
    __shared__ __bf16 sA[128 * 64];
    __shared__ __bf16 sB[128 * 64];

    const int tid = threadIdx.x;
    const int nbn = N >> 7;
    const int nwg = (M >> 7) * nbn;
    const int wg  = ((int)blockIdx.x & 7) * (nwg >> 3) + ((int)blockIdx.x >> 3);
    const int row0 = (wg / nbn) * 128, col0 = (wg % nbn) * 128;
    const int lane = tid & 63, w = tid >> 6, lr = lane & 15, lk = lane >> 4;
    const int wm = w >> 1, wn = w & 1;
    const int srow = tid >> 3;
    const int schk = tid & 7;

    bf16x8 ra[4], rb[4];
    f32x4 acc[4][4];
    #pragma unroll
    for (int a = 0; a < 4; ++a)
        #pragma unroll
        for (int b = 0; b < 4; ++b) acc[a][b] = (f32x4){0.f, 0.f, 0.f, 0.f};

    const int nkt = K >> 6;
    {
        const int kc = schk * 8;
        #pragma unroll
        for (int u = 0; u < 4; ++u) {
            const int r = u * 32 + srow;
            ra[u] = ld_any(X  + (size_t)(row0 + r) * K + kc);
            rb[u] = ld_any(Wt + (size_t)(col0 + r) * K + kc);
        }
    }
    for (int kt = 0; kt < nkt; ++kt) {
        __syncthreads();
        #pragma unroll
        for (int u = 0; u < 4; ++u) {
            const int r = u * 32 + srow;
            *(bf16x8*)&sA[r * 64 + ((schk ^ (r & 7)) * 8)] = ra[u];
            *(bf16x8*)&sB[r * 64 + ((schk ^ (r & 7)) * 8)] = rb[u];
        }
        __syncthreads();
        if (kt + 1 < nkt) {
            const int kc = (kt + 1) * 64 + schk * 8;
            #pragma unroll
            for (int u = 0; u < 4; ++u) {
                const int r = u * 32 + srow;
                ra[u] = ld_any(X  + (size_t)(row0 + r) * K + kc);
                rb[u] = ld_any(Wt + (size_t)(col0 + r) * K + kc);
            }
        }
        #pragma unroll
        for (int kk = 0; kk < 2; ++kk) {
            bf16x8 af[4], bf[4];
            #pragma unroll
            for (int mi = 0; mi < 4; ++mi) {
                const int r = wm * 64 + mi * 16 + lr;
                af[mi] = *(const bf16x8*)&sA[r * 64 + (((kk * 4 + lk) ^ (r & 7)) * 8)];
            }
            #pragma unroll
            for (int ni = 0; ni < 4; ++ni) {
                const int r = wn * 64 + ni * 16 + lr;
                bf[ni] = *(const bf16x8*)&sB[r * 64 + (((kk * 4 + lk) ^ (r & 7)) * 8)];
            }
            #pragma unroll
            for (int mi = 0; mi < 4; ++mi)
                #pragma unroll
                for (int ni = 0; ni < 4; ++ni)
                    acc[mi][ni] = mfma16x16x32(af[mi], bf[ni], acc[mi][ni]);
        }
    }

    #pragma unroll
    for (int ni = 0; ni < 4; ++ni) {
        const int n = col0 + wn * 64 + ni * 16 + lr;
        const float bv = bias[n];
        #pragma unroll
        for (int mi = 0; mi < 4; ++mi) {
            const int m0 = row0 + wm * 64 + mi * 16 + lk * 4;
            if (MODE == 0) {
                #pragma unroll
                for (int i = 0; i < 4; ++i)
                    ((__bf16*)outp)[(size_t)(m0 + i) * N + n] =
                        (__bf16)((acc[mi][ni][i] + bv) * scale);
            } else if (MODE == 1) {
                bf16x4 v4;
                #pragma unroll
                for (int i = 0; i < 4; ++i) v4[i] = (__bf16)(acc[mi][ni][i] + bv);
                *(bf16x4*)((__bf16*)outp + ((size_t)(m0 >> 10) << 20)
                           + (size_t)n * L_ + (m0 & 1023)) = v4;
            } else {
                #pragma unroll
                for (int i = 0; i < 4; ++i)
                    ((float*)outp)[(size_t)(m0 + i) * N + n] = acc[mi][ni][i] + bv;
            }
        }
    }
}

// ---------------------------------------------------------------------------
// Attention v5: block = (b, h, 64 q-rows), 4 waves; wave w owns q-rows
// [w*16, w*16+16) across ALL 1024 keys (wave-local softmax/arel, no atomics).
// K/V staged per-block in XOR-swizzled LDS tiles (64x64, dbuf, reg-prefetch),
// shared by all waves; one barrier per k-tile. PV A-frags via v4's verified
// shuffle recipe; ctx + rel-term accumulate in registers across tiles.
// ---------------------------------------------------------------------------
__global__ __launch_bounds__(256, 3) void attn_v5(
    const __bf16* __restrict__ Q, const __bf16* __restrict__ K,
    const __bf16* __restrict__ Vt, const int* __restrict__ mask,
    const float* __restrict__ relg, __bf16* __restrict__ ctx,
    float* __restrict__ attn0)
{
    __shared__ __bf16 sK[2][64 * 64];     // [key][d], chunk-swizzled
    __shared__ __bf16 sV[2][64 * 64];     // [d][key], chunk-swizzled
    __shared__ __bf16 s_rq[64 * 72];      // rq[qlocal][j], bf16
    __shared__ __bf16 s_arel[64 * 72];    // arel[qlocal][bucket], bf16
    __shared__ float s_sums[64];
    __shared__ unsigned s_mbits[32];

    const int tid = threadIdx.x;
    const int wg = ((int)blockIdx.x & 7) * 256 + ((int)blockIdx.x >> 3);
    const int qt = wg & 15, h = (wg >> 4) & 15, b = wg >> 8;
    const int q0 = qt * 64;
    const int lane = tid & 63, w = tid >> 6, lr = lane & 15, lk = lane >> 4;
    const size_t bh = (size_t)b * (L_ * D_) + (size_t)h * DPH_;
    const int qw = q0 + w * 16;           // wave's q base (global)
    const int ql = w * 16;                // wave's q base (block-local)

    // staging geometry: thread t handles chunks u*256+t (u=0,1) of each tile
    const int strow = tid >> 3;                  // 0..31
    const int scg   = (tid & 7) ^ (strow & 7);   // pre-swizzled global chunk
    const __bf16* Kgp = K + bh + (size_t)strow * D_ + scg * 8;
    const __bf16* Vgp = Vt + ((size_t)b << 20)
                      + (size_t)(h * DPH_ + strow) * L_ + scg * 8;

    // Q fragments: lane lr -> q-row qw+lr
    const __bf16* qp = Q + bh + (size_t)(qw + lr) * D_ + 8 * lk;
    const bf16x8 qf0 = *(const bf16x8*)qp;
    const bf16x8 qf1 = *(const bf16x8*)(qp + 32);

    // ---- setup: mask bitset, zero arel, rq via MFMA, preload tile 0 ----
    #pragma unroll
    for (int rr = 0; rr < 4; ++rr) {
        const int k = rr * 256 + w * 64 + lane;
        const unsigned long long bal = __ballot(mask[b * L_ + k] != 0);
        if (lane == 0) {
            s_mbits[rr * 8 + w * 2]     = (unsigned)bal;
            s_mbits[rr * 8 + w * 2 + 1] = (unsigned)(bal >> 32);
        }
    }
    for (int i = tid; i < 64 * 72; i += 256) s_arel[i] = (__bf16)0.f;

    #pragma unroll
    for (int jt = 0; jt < 5; ++jt) {             // each wave: all j for its rows
        const int jr = jt * 16 + lr;
        const int jc = jr > 64 ? 64 : jr;
        const float* rp = relg + jc * 64 + 8 * lk;
        f32x4 rq = {0.f, 0.f, 0.f, 0.f};
        rq = mfma16x16x32(ld_any(rp), qf0, rq);
        rq = mfma16x16x32(ld_any(rp + 32), qf1, rq);
        #pragma unroll
        for (int i = 0; i < 4; ++i) {
            const int jj = jt * 16 + lk * 4 + i;
            if (jj <= 64) s_rq[(ql + lr) * 72 + jj] = (__bf16)rq[i];
        }
    }

    bf16x8 rk0 = *(const bf16x8*)(Kgp);
    bf16x8 rk1 = *(const bf16x8*)(Kgp + 32 * (size_t)D_);
    bf16x8 rv0 = *(const bf16x8*)(Vgp);
    bf16x8 rv1 = *(const bf16x8*)(Vgp + 32 * (size_t)L_);
    __syncthreads();   // barrier A

    const float rq0  = (float)s_rq[(ql + lr) * 72 + 0];
    const float rq64 = (float)s_rq[(ql + lr) * 72 + 64];

    float sum = 0.f, c0 = 0.f, c64 = 0.f;
    f32x4 pvacc[4];
    #pragma unroll
    for (int dt = 0; dt < 4; ++dt) pvacc[dt] = (f32x4){0.f, 0.f, 0.f, 0.f};
    float* a0p = attn0 + ((size_t)b * L_ + qw + lr) * L_;
    const int sw = lr & 7;
    const int s0l = lr + 32 * (lk & 1);
    const int s1l = s0l + 16;
    const bool hisel = (lk >> 1) != 0;

    for (int it = 0; it < 16; ++it) {
        const int cur = it & 1;
        const int k0 = it * 64;
        // write prefetched regs -> LDS (linear dest; source was pre-swizzled)
        {
            __bf16* kd = &sK[cur][tid * 8];
            __bf16* vd = &sV[cur][tid * 8];
            *(bf16x8*)kd = rk0;  *(bf16x8*)(kd + 2048) = rk1;
            *(bf16x8*)vd = rv0;  *(bf16x8*)(vd + 2048) = rv1;
        }
        __syncthreads();   // single barrier per tile (dbuf)
        if (it < 15) {
            const size_t ko = (size_t)(k0 + 64) * D_;
            rk0 = *(const bf16x8*)(Kgp + ko);
            rk1 = *(const bf16x8*)(Kgp + ko + 32 * (size_t)D_);
            rv0 = *(const bf16x8*)(Vgp + k0 + 64);
            rv1 = *(const bf16x8*)(Vgp + k0 + 64 + 32 * (size_t)L_);
        }

        const __bf16* kb = sK[cur];
        const __bf16* vb = sV[cur];

        // ---- QK^T: p[kt][i] = S(q=qw+lr, key=k0+kt*16+lk*4+i) ----
        float p[4][4];
        #pragma unroll
        for (int kt = 0; kt < 4; ++kt) {
            const int rb = (kt * 16 + lr) * 64;
            const bf16x8 a0 = *(const bf16x8*)&kb[rb + ((lk ^ sw) * 8)];
            const bf16x8 a1 = *(const bf16x8*)&kb[rb + (((lk + 4) ^ sw) * 8)];
            f32x4 acc = {0.f, 0.f, 0.f, 0.f};
            acc = mfma16x16x32(a0, qf0, acc);
            acc = mfma16x16x32(a1, qf1, acc);
            #pragma unroll
            for (int i = 0; i < 4; ++i) p[kt][i] = acc[i];
        }

        // ---- bias + mask + exp + sums + arel ----
        const unsigned mw0 = s_mbits[(k0 >> 5)];
        const unsigned mw1 = s_mbits[(k0 >> 5) + 1];
        const int side = (k0 <= qw - 95) ? -1 : ((k0 >= qw + 47) ? 1 : 0);
        if (side == 0) {
            #pragma unroll
            for (int kt = 0; kt < 4; ++kt) {
                const unsigned mword = kt < 2 ? mw0 : mw1;
                #pragma unroll
                for (int i = 0; i < 4; ++i) {
                    const int k = k0 + kt * 16 + lk * 4 + i;
                    const int dd = k - (qw + lr);
                    int j = dd + MAXREL_;
                    j = j < 0 ? 0 : (j > 64 ? 64 : j);
                    const float bias = (float)s_rq[(ql + lr) * 72 + j];
                    const float e = ((mword >> (k & 31)) & 1u)
                                  ? 0.f : __expf(p[kt][i] + bias);
                    p[kt][i] = e;
                    sum += e;
                    if (dd <= -MAXREL_)      c0  += e;
                    else if (dd >= MAXREL_)  c64 += e;
                    else s_arel[(ql + lr) * 72 + dd + MAXREL_] = (__bf16)e;
                }
            }
        } else {
            const float bias = side < 0 ? rq0 : rq64;
            float cacc = 0.f;
            #pragma unroll
            for (int kt = 0; kt < 4; ++kt) {
                const unsigned mword = kt < 2 ? mw0 : mw1;
                #pragma unroll
                for (int i = 0; i < 4; ++i) {
                    const int k = k0 + kt * 16 + lk * 4 + i;
                    const float e = ((mword >> (k & 31)) & 1u)
                                  ? 0.f : __expf(p[kt][i] + bias);
                    p[kt][i] = e;
                    cacc += e;
                }
            }
            sum += cacc;
            if (side < 0) c0 += cacc; else c64 += cacc;
        }

        // ---- attn0 (h==0): unnormalized now, rescaled at end ----
        if (h == 0) {
            #pragma unroll
            for (int kt = 0; kt < 4; ++kt) {
                f32x4 st;
                #pragma unroll
                for (int i = 0; i < 4; ++i) st[i] = p[kt][i];
                *(f32x4*)&a0p[k0 + kt * 16 + lk * 4] = st;
            }
        }

        // ---- pack p -> bf16 pairs ----
        unsigned pk[4][2];
        #pragma unroll
        for (int kt = 0; kt < 4; ++kt)
            #pragma unroll
            for (int hf = 0; hf < 2; ++hf) {
                union { unsigned u; __bf16 x[2]; } t;
                t.x[0] = (__bf16)p[kt][2 * hf];
                t.x[1] = (__bf16)p[kt][2 * hf + 1];
                pk[kt][hf] = t.u;
            }

        // ---- PV: 2 x 32-key steps; A-frag via shuffles (v4 recipe) ----
        #pragma unroll
        for (int s = 0; s < 2; ++s) {
            union { unsigned u[4]; bf16x8 v; } ua;
            {
                const unsigned aE0 = __shfl((int)pk[2 * s][0],     s0l, 64);
                const unsigned aO0 = __shfl((int)pk[2 * s + 1][0], s0l, 64);
                const unsigned aE1 = __shfl((int)pk[2 * s][1],     s0l, 64);
                const unsigned aO1 = __shfl((int)pk[2 * s + 1][1], s0l, 64);
                const unsigned bE0 = __shfl((int)pk[2 * s][0],     s1l, 64);
                const unsigned bO0 = __shfl((int)pk[2 * s + 1][0], s1l, 64);
                const unsigned bE1 = __shfl((int)pk[2 * s][1],     s1l, 64);
                const unsigned bO1 = __shfl((int)pk[2 * s + 1][1], s1l, 64);
                ua.u[0] = hisel ? aO0 : aE0;
                ua.u[1] = hisel ? aO1 : aE1;
                ua.u[2] = hisel ? bO0 : bE0;
                ua.u[3] = hisel ? bO1 : bE1;
            }
            #pragma unroll
            for (int dt = 0; dt < 4; ++dt) {
                const bf16x8 bfv = *(const bf16x8*)
                    &vb[(dt * 16 + lr) * 64 + (((4 * s + lk) ^ sw) * 8)];
                pvacc[dt] = mfma16x16x32(ua.v, bfv, pvacc[dt]);
            }
        }
    }

    // ---- wave-local sums + edge buckets ----
    sum += __shfl_xor(sum, 16, 64); sum += __shfl_xor(sum, 32, 64);
    c0  += __shfl_xor(c0, 16, 64);  c0  += __shfl_xor(c0, 32, 64);
    c64 += __shfl_xor(c64, 16, 64); c64 += __shfl_xor(c64, 32, 64);
    if (lane < 16) {
        s_sums[ql + lr] = sum;
        s_arel[(ql + lr) * 72 + 0]  = (__bf16)c0;
        s_arel[(ql + lr) * 72 + 64] = (__bf16)c64;
    }
    __syncthreads();

    // ---- stage relT[d][j] over sK arena ----
    __bf16* rT = (__bf16*)sK;      // [64][72]
    for (int i = tid; i < NREL_ * DPH_; i += 256)
        rT[(i & 63) * 72 + (i >> 6)] = (__bf16)relg[i];
    __syncthreads();

    // ---- rel-term MFMAs + j=64 rank-1 + normalize + store ctx ----
    const bf16x8 af1 = *(const bf16x8*)&s_arel[(ql + lr) * 72 + 8 * lk];
    const bf16x8 af2 = *(const bf16x8*)&s_arel[(ql + lr) * 72 + 32 + 8 * lk];
    float a64[4], inv[4];
    #pragma unroll
    for (int i = 0; i < 4; ++i) {
        a64[i] = (float)s_arel[(ql + lk * 4 + i) * 72 + 64];
        inv[i] = 1.f / s_sums[ql + lk * 4 + i];
    }
    #pragma unroll
    for (int dt = 0; dt < 4; ++dt) {
        const bf16x8 b1 = *(const bf16x8*)&rT[(dt * 16 + lr) * 72 + 8 * lk];
        const bf16x8 b2 = *(const bf16x8*)&rT[(dt * 16 + lr) * 72 + 32 + 8 * lk];
        pvacc[dt] = mfma16x16x32(af1, b1, pvacc[dt]);
        pvacc[dt] = mfma16x16x32(af2, b2, pvacc[dt]);
        const float r64 = (float)rT[(dt * 16 + lr) * 72 + 64];
        #pragma unroll
        for (int i = 0; i < 4; ++i) {
            const float outv = (pvacc[dt][i] + a64[i] * r64) * inv[i];
            ctx[((size_t)b * L_ + q0 + ql + lk * 4 + i) * D_
                + h * DPH_ + dt * 16 + lr] = (__bf16)outv;
        }
    }

    // ---- attn0 rescale (h==0 blocks only) ----
    if (h == 0) {
        #pragma unroll 4
        for (int n = 0; n < 16; ++n) {
            const float invr = 1.f / s_sums[ql + n];
            float* ap = attn0 + ((size_t)b * L_ + q0 + ql + n) * L_ + lane * 16;
            #pragma unroll
            for (int c = 0; c < 4; ++c) {
                f32x4 v = *(f32x4*)&ap[c * 4];
                #pragma unroll
                for (int i = 0; i < 4; ++i) v[i] *= invr;
                *(f32x4*)&ap[c * 4] = v;
            }
        }
    }
}

extern "C" void kernel_launch(void* const* d_in, const int* in_sizes, int n_in,
                              void* d_out, int out_size, void* d_ws, size_t ws_size,
                              hipStream_t stream) {
    const float* key   = (const float*)d_in[0];
    const float* value = (const float*)d_in[1];
    const float* query = (const float*)d_in[2];
    const int*   mask  = (const int*)d_in[3];
    const float* Wq = (const float*)d_in[4];
    const float* bq = (const float*)d_in[5];
    const float* Wk = (const float*)d_in[6];
    const float* bk = (const float*)d_in[7];
    const float* Wv = (const float*)d_in[8];
    const float* bv = (const float*)d_in[9];
    const float* Wo = (const float*)d_in[10];
    const float* bo = (const float*)d_in[11];
    const float* relg = (const float*)d_in[12];

    float* out   = (float*)d_out;
    float* attn0 = out + (size_t)B_ * L_ * D_;

    char* ws = (char*)d_ws;
    __bf16* Qw   = (__bf16*)(ws);
    __bf16* Kw   = (__bf16*)(ws + ((size_t)16 << 20));
    __bf16* Vtw  = (__bf16*)(ws + ((size_t)32 << 20));
    __bf16* Ctxw = (__bf16*)(ws + ((size_t)48 << 20));

    const dim3 blk(256);
    const int M = B_ * L_;
    const int ngemm = (M / 128) * (D_ / 128);   // 512

    gemm128<0, float><<<ngemm, blk, 0, stream>>>(query, Wq, bq, Qw, M, D_, D_, 0.125f);
    gemm128<0, float><<<ngemm, blk, 0, stream>>>(key,   Wk, bk, Kw, M, D_, D_, 1.0f);
    gemm128<1, float><<<ngemm, blk, 0, stream>>>(value, Wv, bv, Vtw, M, D_, D_, 1.0f);

    attn_v5<<<B_ * H_ * (L_ / 64), blk, 0, stream>>>(
        Qw, Kw, Vtw, mask, relg, Ctxw, attn0);

    gemm128<2, __bf16><<<ngemm, blk, 0, stream>>>(Ctxw, Wo, bo, out, M, D_, D_, 1.0f);
}